// Round 5
// baseline (299.091 us; speedup 1.0000x reference)
//
#include <hip/hip_runtime.h>
#include <math.h>

#define S 1024
#define RADIUS 512
#define NIMG 32   // 16 "output" images then 16 "target" images
#define PBX 129   // pass-B blocks per image (u-groups of 4)

// ---------------------------------------------------------------------------
// Complex helpers
// ---------------------------------------------------------------------------
__device__ __forceinline__ float2 cmul(float2 a, float2 b) {
    return make_float2(a.x * b.x - a.y * b.y, a.x * b.y + a.y * b.x);
}
__device__ __forceinline__ float2 cadd(float2 a, float2 b) { return make_float2(a.x + b.x, a.y + b.y); }
__device__ __forceinline__ float2 csub(float2 a, float2 b) { return make_float2(a.x - b.x, a.y - b.y); }

// W_16^k, k=0..7  (used by pass-A fft16)
__device__ const float2 C16[8] = {
    {1.0f, 0.0f},
    {0.92387953251128674f, -0.38268343236508978f},
    {0.70710678118654757f, -0.70710678118654746f},
    {0.38268343236508984f, -0.92387953251128674f},
    {0.0f, -1.0f},
    {-0.38268343236508973f, -0.92387953251128674f},
    {-0.70710678118654746f, -0.70710678118654757f},
    {-0.92387953251128663f, -0.38268343236508989f},
};
// W_8^k, k=0..3
__device__ const float2 C8T[4] = {
    {1.0f, 0.0f},
    {0.70710678118654757f, -0.70710678118654746f},
    {0.0f, -1.0f},
    {-0.70710678118654746f, -0.70710678118654757f},
};
// Twiddle tables (pass B — replaces all sincosf):
// W512^m
__device__ const float2 W512T[8] = {
    {1.0f, 0.0f},
    {0.99992470183914454f, -0.012271538285719925f},
    {0.99969881869620425f, -0.024541228522912288f},
    {0.99932238458834954f, -0.036807222941358832f},
    {0.99879545620517241f, -0.049067674327418015f},
    {0.99811811290014918f, -0.061320736302208578f},
    {0.99729045667869021f, -0.073564563599667426f},
    {0.99631261218277800f, -0.085797312344439894f},
};
// W64^k
__device__ const float2 W64T[8] = {
    {1.0f, 0.0f},
    {0.99518472667219693f, -0.098017140329560604f},
    {0.98078528040323044f, -0.19509032201612825f},
    {0.95694033573220886f, -0.29028467725446233f},
    {0.92387953251128674f, -0.38268343236508978f},
    {0.88192126434835505f, -0.47139673682599764f},
    {0.83146961230254524f, -0.55557023301960218f},
    {0.77301045336273699f, -0.63439328416364549f},
};
// W1024^{rev3(a)}
__device__ const float2 TAt[8] = {
    {1.0f, 0.0f},
    {0.99969881869620425f, -0.024541228522912288f},
    {0.99992470183914454f, -0.012271538285719925f},
    {0.99932238458834954f, -0.036807222941358832f},
    {0.99998117528260111f, -0.0061358846491544753f},
    {0.99952941750109314f, -0.030674803176636626f},
    {0.99983058179582340f, -0.018406729905804820f},
    {0.99907772775264536f, -0.042938256934940820f},
};
// W128^{rev3(c)}
__device__ const float2 TBt[8] = {
    {1.0f, 0.0f},
    {0.98078528040323044f, -0.19509032201612825f},
    {0.99518472667219693f, -0.098017140329560604f},
    {0.95694033573220886f, -0.29028467725446233f},
    {0.99879545620517241f, -0.049067674327418015f},
    {0.97003125319454397f, -0.24298017990326390f},
    {0.98917650996478101f, -0.14673047445536175f},
    {0.94154406518302081f, -0.33688985339222005f},
};
// W16^{rev3(d)}
__device__ const float2 TDt[8] = {
    {1.0f, 0.0f},
    {0.0f, -1.0f},
    {0.70710678118654757f, -0.70710678118654746f},
    {-0.70710678118654746f, -0.70710678118654757f},
    {0.92387953251128674f, -0.38268343236508978f},
    {-0.38268343236508973f, -0.92387953251128674f},
    {0.38268343236508984f, -0.92387953251128674f},
    {-0.92387953251128663f, -0.38268343236508989f},
};

// 4 radix-2 DIF stages over 16 register elements (pass A)
__device__ __forceinline__ void fft16(float2 r[16], float2 T) {
    float2 tc[8];
    #pragma unroll
    for (int u = 0; u < 8; ++u) tc[u] = cmul(T, C16[u]);
    #pragma unroll
    for (int u = 0; u < 8; ++u) {
        float2 a = r[u], b = r[u + 8];
        r[u] = cadd(a, b);
        r[u + 8] = cmul(csub(a, b), tc[u]);
    }
    T = cmul(T, T);
    #pragma unroll
    for (int u = 0; u < 4; ++u) tc[u] = cmul(T, C16[2 * u]);
    #pragma unroll
    for (int g = 0; g < 2; ++g)
        #pragma unroll
        for (int u = 0; u < 4; ++u) {
            int lo = g * 8 + u;
            float2 a = r[lo], b = r[lo + 4];
            r[lo] = cadd(a, b);
            r[lo + 4] = cmul(csub(a, b), tc[u]);
        }
    T = cmul(T, T);
    #pragma unroll
    for (int u = 0; u < 2; ++u) tc[u] = cmul(T, C16[4 * u]);
    #pragma unroll
    for (int g = 0; g < 4; ++g)
        #pragma unroll
        for (int u = 0; u < 2; ++u) {
            int lo = g * 4 + u;
            float2 a = r[lo], b = r[lo + 2];
            r[lo] = cadd(a, b);
            r[lo + 2] = cmul(csub(a, b), tc[u]);
        }
    T = cmul(T, T);
    #pragma unroll
    for (int g = 0; g < 8; ++g) {
        int lo = g * 2;
        float2 a = r[lo], b = r[lo + 1];
        r[lo] = cadd(a, b);
        r[lo + 1] = cmul(csub(a, b), T);
    }
}

// 3 radix-2 DIF stages over TWO independent 8-element sets (shared twiddles).
__device__ __forceinline__ void fft8x2(float2 a[8], float2 b[8], float2 T) {
    float2 tc[4];
    #pragma unroll
    for (int u = 0; u < 4; ++u) tc[u] = cmul(T, C8T[u]);
    #pragma unroll
    for (int u = 0; u < 4; ++u) {
        float2 xa = a[u], ya = a[u + 4];
        a[u] = cadd(xa, ya);
        a[u + 4] = cmul(csub(xa, ya), tc[u]);
        float2 xb = b[u], yb = b[u + 4];
        b[u] = cadd(xb, yb);
        b[u + 4] = cmul(csub(xb, yb), tc[u]);
    }
    T = cmul(T, T);
    #pragma unroll
    for (int u = 0; u < 2; ++u) tc[u] = cmul(T, C8T[2 * u]);
    #pragma unroll
    for (int g = 0; g < 2; ++g)
        #pragma unroll
        for (int u = 0; u < 2; ++u) {
            int lo = g * 4 + u;
            float2 xa = a[lo], ya = a[lo + 2];
            a[lo] = cadd(xa, ya);
            a[lo + 2] = cmul(csub(xa, ya), tc[u]);
            float2 xb = b[lo], yb = b[lo + 2];
            b[lo] = cadd(xb, yb);
            b[lo + 2] = cmul(csub(xb, yb), tc[u]);
        }
    T = cmul(T, T);
    #pragma unroll
    for (int g = 0; g < 4; ++g) {
        int lo = g * 2;
        float2 xa = a[lo], ya = a[lo + 1];
        a[lo] = cadd(xa, ya);
        a[lo + 1] = cmul(csub(xa, ya), T);
        float2 xb = b[lo], yb = b[lo + 1];
        b[lo] = cadd(xb, yb);
        b[lo + 1] = cmul(csub(xb, yb), T);
    }
}

// Last 2 DIF stages (1024-pt, pass A): quad-perm shuffles (true DPP) across c = tau&3
__device__ __forceinline__ void fft_last2(float2 r[16], int c) {
    #pragma unroll
    for (int m = 0; m < 16; ++m) {
        float vx = __shfl_xor(r[m].x, 2, 64);
        float vy = __shfl_xor(r[m].y, 2, 64);
        if (c & 2) {
            float dx = vx - r[m].x, dy = vy - r[m].y;
            if (c & 1) { r[m].x = dy; r[m].y = -dx; }
            else       { r[m].x = dx; r[m].y = dy; }
        } else {
            r[m].x += vx; r[m].y += vy;
        }
    }
    #pragma unroll
    for (int m = 0; m < 16; ++m) {
        float vx = __shfl_xor(r[m].x, 1, 64);
        float vy = __shfl_xor(r[m].y, 1, 64);
        if (c & 1) { r[m].x = vx - r[m].x; r[m].y = vy - r[m].y; }
        else       { r[m].x += vx; r[m].y += vy; }
    }
}

// Swizzled LDS addr for 1024-pt transpose (pass A)
__device__ __forceinline__ int A1x(int n) {
    int j = n >> 6;
    return (n & ~63) | ((n & 63) ^ (j << 2));
}

__device__ __forceinline__ int bitrev3(int x) {
    return ((x & 1) << 2) | (x & 2) | ((x >> 2) & 1);
}

// ---------------------------------------------------------------------------
// Pass A: packed row-pair FFTs (unchanged — validated, ~80% of achievable HBM).
// ---------------------------------------------------------------------------
__global__ __launch_bounds__(512)
void fft_rows(const float* __restrict__ outp, const float* __restrict__ tgtp,
              float2* __restrict__ WpT, int imgBase) {
    __shared__ float2 buf[8 * 1024];
    const int t = threadIdx.x;
    const int w = t >> 6, tau = t & 63;
    const int yy = blockIdx.x * 8 + w;
    const int i = blockIdx.y, g = imgBase + i;
    const float* img = (g < 16 ? outp : tgtp) + (size_t)(g & 15) * S * S;
    const float* r0 = img + (size_t)(2 * yy) * S;
    const float* r1 = r0 + S;

    float2 r[16];
    #pragma unroll
    for (int j = 0; j < 16; ++j) r[j] = make_float2(r0[64 * j + tau], r1[64 * j + tau]);

    float2 T;
    { float sv, cv; sincosf(-6.283185307179586f * (float)tau / 1024.0f, &sv, &cv); T = make_float2(cv, sv); }
    fft16(r, T);

    float2* mybuf = buf + (w << 10);
    #pragma unroll
    for (int j = 0; j < 16; ++j) mybuf[A1x(64 * j + tau)] = r[j];
    const int b = tau >> 2, c = tau & 3;
    #pragma unroll
    for (int m = 0; m < 16; ++m) r[m] = mybuf[(b << 6) + 4 * (m ^ b) + c];

    { float sv, cv; sincosf(-6.283185307179586f * (float)c / 64.0f, &sv, &cv); T = make_float2(cv, sv); }
    fft16(r, T);
    fft_last2(r, c);

    #pragma unroll
    for (int m = 0; m < 16; ++m) {
        int n = (b << 6) + 4 * m + c;
        int k = (int)(__brev((unsigned)n) >> 22);
        mybuf[k ^ (w << 1)] = r[m];
    }
    __syncthreads();

    const int yy0 = blockIdx.x * 8;
    float2* dst = WpT + (size_t)i * 512 * 1024;
    #pragma unroll
    for (int q = 0; q < 16; ++q) {
        int idx = q * 512 + t;
        int uu = idx >> 3, wv = idx & 7;
        float2 val = buf[(wv << 10) | (uu ^ (wv << 1))];
        dst[(size_t)uu * 512 + yy0 + wv] = val;
    }
}

// ---------------------------------------------------------------------------
// Pass B: Hermitian split + dual 512-pt FFT as radix-8^3 (3x fft8x2 in-register,
// 2 LDS transposes, ZERO shuffles, ZERO sincosf) + combine + bin.
// LDS: 4 KB/wave transpose buffer (A,B time-share; in-wave DS ordering) + bins.
// 18.4 KB/block -> 8 blocks/CU = 32 waves/CU possible.
// Unified transpose swizzle A(p) = (hi<<6) | (lo ^ (hi<<3) ^ hi), p = 64*hi+lo:
// all four access patterns (write j / read c / write c / read d) are
// bank-conflict-free (verified: low-6 address bits cover all 64 values per
// instruction across the 64 lanes).
// ---------------------------------------------------------------------------
__global__ __launch_bounds__(256, 8)
void fft_cols_bin(const float2* __restrict__ WpT, float* __restrict__ partial, int imgBase) {
    __shared__ float2 tbuf[4 * 512];   // 16 KB: 512-slot buffer per wave
    __shared__ float bins[RADIUS + 1];
    const int t = threadIdx.x;
    const int w = t >> 6, tau = t & 63;
    const int i = blockIdx.y, g = imgBase + i;
    const int u = blockIdx.x * 4 + w;            // 0..515

    for (int j = t; j <= RADIUS; j += 256) bins[j] = 0.0f;
    __syncthreads();

    if (u <= 512) {
        const float2* Wimg = WpT + (size_t)i * 512 * 1024;
        const int mu = (1024 - u) & 1023;
        const float2* rowA = Wimg + (size_t)u * 512;
        const float2* rowM = Wimg + (size_t)mu * 512;

        float2 X0[8], X1[8];
        #pragma unroll
        for (int j = 0; j < 8; ++j) {
            float2 A = rowA[64 * j + tau];
            float2 M = rowM[64 * j + tau];
            X0[j] = make_float2(0.5f * (A.x + M.x), 0.5f * (A.y - M.y));
            X1[j] = make_float2(0.5f * (A.y + M.y), 0.5f * (M.x - A.x));
        }

        const int b3 = tau >> 3, lam = tau & 7;
        // Phase 1: top 3 DIF stages of 512; T = W512^tau = W64^{b3} * W512^{lam}
        fft8x2(X0, X1, cmul(W64T[b3], W512T[lam]));

        // Transpose 1: thread holds position 64j+tau; re-gather so thread
        // (b3,lam) holds sub-array a*=b3, elements j=8c+lam.
        float2* mb = tbuf + (w << 9);
        #pragma unroll
        for (int j = 0; j < 8; ++j) mb[(j << 6) | (tau ^ (j << 3) ^ j)] = X0[j];
        #pragma unroll
        for (int c = 0; c < 8; ++c) X0[c] = mb[(b3 << 6) | (((c ^ b3) << 3) | (lam ^ b3))];
        #pragma unroll
        for (int j = 0; j < 8; ++j) mb[(j << 6) | (tau ^ (j << 3) ^ j)] = X1[j];
        #pragma unroll
        for (int c = 0; c < 8; ++c) X1[c] = mb[(b3 << 6) | (((c ^ b3) << 3) | (lam ^ b3))];

        // Phase 2: middle 3 DIF stages (64-pt sub-DFT); T = W64^{lam}
        fft8x2(X0, X1, W64T[lam]);

        // Transpose 2: re-gather so thread holds one contiguous 8-block:
        // position 64*b3 + 8*lam + d.
        #pragma unroll
        for (int c = 0; c < 8; ++c) mb[(b3 << 6) | (((c ^ b3) << 3) | (lam ^ b3))] = X0[c];
        #pragma unroll
        for (int d = 0; d < 8; ++d) X0[d] = mb[(b3 << 6) | (((lam ^ b3) << 3) | (d ^ b3))];
        #pragma unroll
        for (int c = 0; c < 8; ++c) mb[(b3 << 6) | (((c ^ b3) << 3) | (lam ^ b3))] = X1[c];
        #pragma unroll
        for (int d = 0; d < 8; ++d) X1[d] = mb[(b3 << 6) | (((lam ^ b3) << 3) | (d ^ b3))];

        // Phase 3: plain 8-pt DFT (T = 1; const-folds)
        fft8x2(X0, X1, make_float2(1.0f, 0.0f));

        // Combine + bin. Register d of thread (b3,lam) holds frequency
        // f = rev3(b3) + 8*rev3(lam) + 64*rev3(d)   (0..511)
        const int ra = bitrev3(b3), rc = bitrev3(lam);
        const int fbase = ra + 8 * rc;
        float2 Tc = cmul(TAt[b3], TBt[lam]);         // W1024^{ra + 8*rc}

        const float cu = (u < 512) ? (u + 0.5f) : (u - 1023.5f);
        const float cum = 0.5f - (float)u;           // mirror column coordinate
        const bool dbl = (u >= 1 && u <= 511);

        #pragma unroll
        for (int d = 0; d < 8; ++d) {
            float2 Wv = cmul(Tc, TDt[d]);            // W1024^f
            float2 w1 = cmul(Wv, X1[d]);
            float2 Gp = cadd(X0[d], w1);             // v = f
            float2 Gm = csub(X0[d], w1);             // v = f + 512
            const int f = fbase + 64 * (((d & 1) << 2) | (d & 2) | (d >> 2));
            float p1 = Gp.x * Gp.x + Gp.y * Gp.y;
            float p2 = Gm.x * Gm.x + Gm.y * Gm.y;

            float cv1 = f + 0.5f;
            float cv2 = f - 511.5f;
            float d1 = sqrtf(cu * cu + cv1 * cv1);
            float d2 = sqrtf(cu * cu + cv2 * cv2);
            if (d1 < (float)RADIUS) atomicAdd(&bins[(int)d1], p1);
            if (d2 < (float)RADIUS) atomicAdd(&bins[(int)d2], p2);
            if (dbl) {
                int v1m = (1024 - f) & 1023;
                int v2m = 512 - f;
                float cv1m = (v1m < 512) ? (v1m + 0.5f) : (v1m - 1023.5f);
                float cv2m = (v2m < 512) ? (v2m + 0.5f) : (v2m - 1023.5f);
                float d1m = sqrtf(cum * cum + cv1m * cv1m);
                float d2m = sqrtf(cum * cum + cv2m * cv2m);
                if (d1m < (float)RADIUS) atomicAdd(&bins[(int)d1m], p1);
                if (d2m < (float)RADIUS) atomicAdd(&bins[(int)d2m], p2);
            }
        }
    }
    __syncthreads();
    // per-block partial histogram; every slot written every call (re-poison safe)
    float* dst = partial + ((size_t)g * PBX + blockIdx.x) * RADIUS;
    for (int j = t; j < RADIUS; j += 256) dst[j] = bins[j];
}

// ---------------------------------------------------------------------------
// Fold partials -> rad
// ---------------------------------------------------------------------------
__global__ __launch_bounds__(256)
void reduce_partials(const float* __restrict__ partial, float* __restrict__ rad) {
    int idx = blockIdx.x * 256 + threadIdx.x;    // 0 .. NIMG*RADIUS-1
    if (idx >= NIMG * RADIUS) return;
    int g = idx >> 9, j = idx & (RADIUS - 1);
    const float* p = partial + (size_t)g * PBX * RADIUS + j;
    float s = 0.0f;
    for (int b = 0; b < PBX; ++b) s += p[(size_t)b * RADIUS];
    rad[idx] = s;
}

// ---------------------------------------------------------------------------
// Final: loss = mean(|rad_out - rad_tgt|) / S^2
// ---------------------------------------------------------------------------
__global__ __launch_bounds__(256)
void final_loss(const float* __restrict__ rad, float* __restrict__ out) {
    __shared__ float red[256];
    const int t = threadIdx.x;
    float acc = 0.0f;
    for (int i = t; i < 16 * RADIUS; i += 256) {
        int bb = i >> 9;
        int rr = i & (RADIUS - 1);
        float o = rad[(size_t)bb * RADIUS + rr];
        float gg = rad[(size_t)(bb + 16) * RADIUS + rr];
        acc += fabsf(o - gg);
    }
    red[t] = acc;
    __syncthreads();
    for (int off = 128; off > 0; off >>= 1) {
        if (t < off) red[t] += red[t + off];
        __syncthreads();
    }
    if (t == 0) {
        out[0] = red[0] / ((float)S * (float)S) / (16.0f * (float)RADIUS);
    }
}

extern "C" void kernel_launch(void* const* d_in, const int* in_sizes, int n_in,
                              void* d_out, int out_size, void* d_ws, size_t ws_size,
                              hipStream_t stream) {
    const float* outp = (const float*)d_in[0];
    const float* tgtp = (const float*)d_in[1];
    float* dout = (float*)d_out;

    char* ws = (char*)d_ws;
    float* rad = (float*)ws;                                       // 64 KB
    const size_t partBytes = (size_t)NIMG * PBX * RADIUS * sizeof(float);  // 8.45 MB
    float* partial = (float*)(ws + 65536);
    float2* WpT = (float2*)(ws + 65536 + partBytes);
    const size_t perImg = (size_t)512 * 1024 * sizeof(float2);     // 4 MB / image
    size_t used = 65536 + partBytes;
    size_t avail = (ws_size > used) ? (ws_size - used) : 0;
    int chunk = (int)(avail / perImg);
    if (chunk > NIMG) chunk = NIMG;
    if (chunk < 1) chunk = 1;

    for (int base = 0; base < NIMG; base += chunk) {
        int c = (NIMG - base < chunk) ? (NIMG - base) : chunk;
        fft_rows<<<dim3(64, c), 512, 0, stream>>>(outp, tgtp, WpT, base);
        fft_cols_bin<<<dim3(PBX, c), 256, 0, stream>>>(WpT, partial, base);
    }

    reduce_partials<<<(NIMG * RADIUS + 255) / 256, 256, 0, stream>>>(partial, rad);
    final_loss<<<1, 256, 0, stream>>>(rad, dout);
}

// Round 6
// 253.085 us; speedup vs baseline: 1.1818x; 1.1818x over previous
//
#include <hip/hip_runtime.h>
#include <math.h>

#define S 1024
#define RADIUS 512
#define NIMG 32   // 16 "output" images then 16 "target" images
#define PBX 129   // pass-B blocks per image (u-groups of 4)
#define BSTRIDE 513   // per-wave bin copy stride (floats)

// ---------------------------------------------------------------------------
// Complex helpers
// ---------------------------------------------------------------------------
__device__ __forceinline__ float2 cmul(float2 a, float2 b) {
    return make_float2(a.x * b.x - a.y * b.y, a.x * b.y + a.y * b.x);
}
__device__ __forceinline__ float2 cadd(float2 a, float2 b) { return make_float2(a.x + b.x, a.y + b.y); }
__device__ __forceinline__ float2 csub(float2 a, float2 b) { return make_float2(a.x - b.x, a.y - b.y); }

// W_16^k, k=0..7  (used by pass-A fft16)
__device__ const float2 C16[8] = {
    {1.0f, 0.0f},
    {0.92387953251128674f, -0.38268343236508978f},
    {0.70710678118654757f, -0.70710678118654746f},
    {0.38268343236508984f, -0.92387953251128674f},
    {0.0f, -1.0f},
    {-0.38268343236508973f, -0.92387953251128674f},
    {-0.70710678118654746f, -0.70710678118654757f},
    {-0.92387953251128663f, -0.38268343236508989f},
};
// W_8^k, k=0..3
__device__ const float2 C8T[4] = {
    {1.0f, 0.0f},
    {0.70710678118654757f, -0.70710678118654746f},
    {0.0f, -1.0f},
    {-0.70710678118654746f, -0.70710678118654757f},
};
// Twiddle tables (pass B — no sincosf):
// W512^m
__device__ const float2 W512T[8] = {
    {1.0f, 0.0f},
    {0.99992470183914454f, -0.012271538285719925f},
    {0.99969881869620425f, -0.024541228522912288f},
    {0.99932238458834954f, -0.036807222941358832f},
    {0.99879545620517241f, -0.049067674327418015f},
    {0.99811811290014918f, -0.061320736302208578f},
    {0.99729045667869021f, -0.073564563599667426f},
    {0.99631261218277800f, -0.085797312344439894f},
};
// W64^k
__device__ const float2 W64T[8] = {
    {1.0f, 0.0f},
    {0.99518472667219693f, -0.098017140329560604f},
    {0.98078528040323044f, -0.19509032201612825f},
    {0.95694033573220886f, -0.29028467725446233f},
    {0.92387953251128674f, -0.38268343236508978f},
    {0.88192126434835505f, -0.47139673682599764f},
    {0.83146961230254524f, -0.55557023301960218f},
    {0.77301045336273699f, -0.63439328416364549f},
};
// W1024^{rev3(a)}
__device__ const float2 TAt[8] = {
    {1.0f, 0.0f},
    {0.99969881869620425f, -0.024541228522912288f},
    {0.99992470183914454f, -0.012271538285719925f},
    {0.99932238458834954f, -0.036807222941358832f},
    {0.99998117528260111f, -0.0061358846491544753f},
    {0.99952941750109314f, -0.030674803176636626f},
    {0.99983058179582340f, -0.018406729905804820f},
    {0.99907772775264536f, -0.042938256934940820f},
};
// W128^{rev3(c)}
__device__ const float2 TBt[8] = {
    {1.0f, 0.0f},
    {0.98078528040323044f, -0.19509032201612825f},
    {0.99518472667219693f, -0.098017140329560604f},
    {0.95694033573220886f, -0.29028467725446233f},
    {0.99879545620517241f, -0.049067674327418015f},
    {0.97003125319454397f, -0.24298017990326390f},
    {0.98917650996478101f, -0.14673047445536175f},
    {0.94154406518302081f, -0.33688985339222005f},
};
// W16^{rev3(d)}
__device__ const float2 TDt[8] = {
    {1.0f, 0.0f},
    {0.0f, -1.0f},
    {0.70710678118654757f, -0.70710678118654746f},
    {-0.70710678118654746f, -0.70710678118654757f},
    {0.92387953251128674f, -0.38268343236508978f},
    {-0.38268343236508973f, -0.92387953251128674f},
    {0.38268343236508984f, -0.92387953251128674f},
    {-0.92387953251128663f, -0.38268343236508989f},
};

// 4 radix-2 DIF stages over 16 register elements (pass A)
__device__ __forceinline__ void fft16(float2 r[16], float2 T) {
    float2 tc[8];
    #pragma unroll
    for (int u = 0; u < 8; ++u) tc[u] = cmul(T, C16[u]);
    #pragma unroll
    for (int u = 0; u < 8; ++u) {
        float2 a = r[u], b = r[u + 8];
        r[u] = cadd(a, b);
        r[u + 8] = cmul(csub(a, b), tc[u]);
    }
    T = cmul(T, T);
    #pragma unroll
    for (int u = 0; u < 4; ++u) tc[u] = cmul(T, C16[2 * u]);
    #pragma unroll
    for (int g = 0; g < 2; ++g)
        #pragma unroll
        for (int u = 0; u < 4; ++u) {
            int lo = g * 8 + u;
            float2 a = r[lo], b = r[lo + 4];
            r[lo] = cadd(a, b);
            r[lo + 4] = cmul(csub(a, b), tc[u]);
        }
    T = cmul(T, T);
    #pragma unroll
    for (int u = 0; u < 2; ++u) tc[u] = cmul(T, C16[4 * u]);
    #pragma unroll
    for (int g = 0; g < 4; ++g)
        #pragma unroll
        for (int u = 0; u < 2; ++u) {
            int lo = g * 4 + u;
            float2 a = r[lo], b = r[lo + 2];
            r[lo] = cadd(a, b);
            r[lo + 2] = cmul(csub(a, b), tc[u]);
        }
    T = cmul(T, T);
    #pragma unroll
    for (int g = 0; g < 8; ++g) {
        int lo = g * 2;
        float2 a = r[lo], b = r[lo + 1];
        r[lo] = cadd(a, b);
        r[lo + 1] = cmul(csub(a, b), T);
    }
}

// 3 radix-2 DIF stages over TWO independent 8-element sets (shared twiddles).
__device__ __forceinline__ void fft8x2(float2 a[8], float2 b[8], float2 T) {
    float2 tc[4];
    #pragma unroll
    for (int u = 0; u < 4; ++u) tc[u] = cmul(T, C8T[u]);
    #pragma unroll
    for (int u = 0; u < 4; ++u) {
        float2 xa = a[u], ya = a[u + 4];
        a[u] = cadd(xa, ya);
        a[u + 4] = cmul(csub(xa, ya), tc[u]);
        float2 xb = b[u], yb = b[u + 4];
        b[u] = cadd(xb, yb);
        b[u + 4] = cmul(csub(xb, yb), tc[u]);
    }
    T = cmul(T, T);
    #pragma unroll
    for (int u = 0; u < 2; ++u) tc[u] = cmul(T, C8T[2 * u]);
    #pragma unroll
    for (int g = 0; g < 2; ++g)
        #pragma unroll
        for (int u = 0; u < 2; ++u) {
            int lo = g * 4 + u;
            float2 xa = a[lo], ya = a[lo + 2];
            a[lo] = cadd(xa, ya);
            a[lo + 2] = cmul(csub(xa, ya), tc[u]);
            float2 xb = b[lo], yb = b[lo + 2];
            b[lo] = cadd(xb, yb);
            b[lo + 2] = cmul(csub(xb, yb), tc[u]);
        }
    T = cmul(T, T);
    #pragma unroll
    for (int g = 0; g < 4; ++g) {
        int lo = g * 2;
        float2 xa = a[lo], ya = a[lo + 1];
        a[lo] = cadd(xa, ya);
        a[lo + 1] = cmul(csub(xa, ya), T);
        float2 xb = b[lo], yb = b[lo + 1];
        b[lo] = cadd(xb, yb);
        b[lo + 1] = cmul(csub(xb, yb), T);
    }
}

// Last 2 DIF stages (1024-pt, pass A): quad-perm shuffles across c = tau&3
__device__ __forceinline__ void fft_last2(float2 r[16], int c) {
    #pragma unroll
    for (int m = 0; m < 16; ++m) {
        float vx = __shfl_xor(r[m].x, 2, 64);
        float vy = __shfl_xor(r[m].y, 2, 64);
        if (c & 2) {
            float dx = vx - r[m].x, dy = vy - r[m].y;
            if (c & 1) { r[m].x = dy; r[m].y = -dx; }
            else       { r[m].x = dx; r[m].y = dy; }
        } else {
            r[m].x += vx; r[m].y += vy;
        }
    }
    #pragma unroll
    for (int m = 0; m < 16; ++m) {
        float vx = __shfl_xor(r[m].x, 1, 64);
        float vy = __shfl_xor(r[m].y, 1, 64);
        if (c & 1) { r[m].x = vx - r[m].x; r[m].y = vy - r[m].y; }
        else       { r[m].x += vx; r[m].y += vy; }
    }
}

// Swizzled LDS addr for 1024-pt transpose (pass A)
__device__ __forceinline__ int A1x(int n) {
    int j = n >> 6;
    return (n & ~63) | ((n & 63) ^ (j << 2));
}

__device__ __forceinline__ int bitrev3(int x) {
    return ((x & 1) << 2) | (x & 2) | ((x >> 2) & 1);
}

// ---------------------------------------------------------------------------
// Pass A: packed row-pair FFTs (unchanged — validated, ~80% of achievable HBM).
// ---------------------------------------------------------------------------
__global__ __launch_bounds__(512)
void fft_rows(const float* __restrict__ outp, const float* __restrict__ tgtp,
              float2* __restrict__ WpT, int imgBase) {
    __shared__ float2 buf[8 * 1024];
    const int t = threadIdx.x;
    const int w = t >> 6, tau = t & 63;
    const int yy = blockIdx.x * 8 + w;
    const int i = blockIdx.y, g = imgBase + i;
    const float* img = (g < 16 ? outp : tgtp) + (size_t)(g & 15) * S * S;
    const float* r0 = img + (size_t)(2 * yy) * S;
    const float* r1 = r0 + S;

    float2 r[16];
    #pragma unroll
    for (int j = 0; j < 16; ++j) r[j] = make_float2(r0[64 * j + tau], r1[64 * j + tau]);

    float2 T;
    { float sv, cv; sincosf(-6.283185307179586f * (float)tau / 1024.0f, &sv, &cv); T = make_float2(cv, sv); }
    fft16(r, T);

    float2* mybuf = buf + (w << 10);
    #pragma unroll
    for (int j = 0; j < 16; ++j) mybuf[A1x(64 * j + tau)] = r[j];
    const int b = tau >> 2, c = tau & 3;
    #pragma unroll
    for (int m = 0; m < 16; ++m) r[m] = mybuf[(b << 6) + 4 * (m ^ b) + c];

    { float sv, cv; sincosf(-6.283185307179586f * (float)c / 64.0f, &sv, &cv); T = make_float2(cv, sv); }
    fft16(r, T);
    fft_last2(r, c);

    #pragma unroll
    for (int m = 0; m < 16; ++m) {
        int n = (b << 6) + 4 * m + c;
        int k = (int)(__brev((unsigned)n) >> 22);
        mybuf[k ^ (w << 1)] = r[m];
    }
    __syncthreads();

    const int yy0 = blockIdx.x * 8;
    float2* dst = WpT + (size_t)i * 512 * 1024;
    #pragma unroll
    for (int q = 0; q < 16; ++q) {
        int idx = q * 512 + t;
        int uu = idx >> 3, wv = idx & 7;
        float2 val = buf[(wv << 10) | (uu ^ (wv << 1))];
        dst[(size_t)uu * 512 + yy0 + wv] = val;
    }
}

// ---------------------------------------------------------------------------
// Pass B: Hermitian split + dual 512-pt FFT as radix-8^3 (3x fft8x2 in-register,
// 2 LDS transposes, zero shuffles, zero sincosf) + combine + bin.
// launch_bounds(256,4): VGPR cap 128 — the 64 live data VGPRs (X0,X1) MUST
// stay register-resident (round-5 lesson: (256,8) forced VGPR=32 -> 470 MB
// of scratch spill traffic, +40 us).
// Per-wave private bin histograms (4 copies) kill inter-wave atomic contention.
// LDS: 16 KB transpose + 8.2 KB bins = 24.6 KB/block.
// ---------------------------------------------------------------------------
__global__ __launch_bounds__(256, 4)
void fft_cols_bin(const float2* __restrict__ WpT, float* __restrict__ partial, int imgBase) {
    __shared__ float2 tbuf[4 * 512];          // 16 KB: 512-slot buffer per wave
    __shared__ float bins[4 * BSTRIDE];       // per-wave histogram copies
    const int t = threadIdx.x;
    const int w = t >> 6, tau = t & 63;
    const int i = blockIdx.y, g = imgBase + i;
    const int u = blockIdx.x * 4 + w;         // 0..515

    for (int j = t; j < 4 * BSTRIDE; j += 256) bins[j] = 0.0f;
    __syncthreads();
    float* mybins = bins + w * BSTRIDE;

    if (u <= 512) {
        const float2* Wimg = WpT + (size_t)i * 512 * 1024;
        const int mu = (1024 - u) & 1023;
        const float2* rowA = Wimg + (size_t)u * 512;
        const float2* rowM = Wimg + (size_t)mu * 512;

        float2 X0[8], X1[8];
        #pragma unroll
        for (int j = 0; j < 8; ++j) {
            float2 A = rowA[64 * j + tau];
            float2 M = rowM[64 * j + tau];
            X0[j] = make_float2(0.5f * (A.x + M.x), 0.5f * (A.y - M.y));
            X1[j] = make_float2(0.5f * (A.y + M.y), 0.5f * (M.x - A.x));
        }

        const int b3 = tau >> 3, lam = tau & 7;
        // Phase 1: top 3 DIF stages of 512; T = W512^tau = W64^{b3} * W512^{lam}
        fft8x2(X0, X1, cmul(W64T[b3], W512T[lam]));

        // Transpose 1 (wave-private, swizzled, conflict-free)
        float2* mb = tbuf + (w << 9);
        #pragma unroll
        for (int j = 0; j < 8; ++j) mb[(j << 6) | (tau ^ (j << 3) ^ j)] = X0[j];
        #pragma unroll
        for (int c = 0; c < 8; ++c) X0[c] = mb[(b3 << 6) | (((c ^ b3) << 3) | (lam ^ b3))];
        #pragma unroll
        for (int j = 0; j < 8; ++j) mb[(j << 6) | (tau ^ (j << 3) ^ j)] = X1[j];
        #pragma unroll
        for (int c = 0; c < 8; ++c) X1[c] = mb[(b3 << 6) | (((c ^ b3) << 3) | (lam ^ b3))];

        // Phase 2: middle 3 DIF stages (64-pt sub-DFT); T = W64^{lam}
        fft8x2(X0, X1, W64T[lam]);

        // Transpose 2
        #pragma unroll
        for (int c = 0; c < 8; ++c) mb[(b3 << 6) | (((c ^ b3) << 3) | (lam ^ b3))] = X0[c];
        #pragma unroll
        for (int d = 0; d < 8; ++d) X0[d] = mb[(b3 << 6) | (((lam ^ b3) << 3) | (d ^ b3))];
        #pragma unroll
        for (int c = 0; c < 8; ++c) mb[(b3 << 6) | (((c ^ b3) << 3) | (lam ^ b3))] = X1[c];
        #pragma unroll
        for (int d = 0; d < 8; ++d) X1[d] = mb[(b3 << 6) | (((lam ^ b3) << 3) | (d ^ b3))];

        // Phase 3: plain 8-pt DFT (T = 1)
        fft8x2(X0, X1, make_float2(1.0f, 0.0f));

        // Combine + bin. Register d of thread (b3,lam) holds frequency
        // f = rev3(b3) + 8*rev3(lam) + 64*rev3(d)
        const int ra = bitrev3(b3), rc = bitrev3(lam);
        const int fbase = ra + 8 * rc;
        float2 Tc = cmul(TAt[b3], TBt[lam]);  // W1024^{ra + 8*rc}

        const float cu = (u < 512) ? (u + 0.5f) : (u - 1023.5f);
        const float cum = 0.5f - (float)u;    // mirror column coordinate
        const bool dbl = (u >= 1 && u <= 511);

        #pragma unroll
        for (int d = 0; d < 8; ++d) {
            float2 Wv = cmul(Tc, TDt[d]);     // W1024^f
            float2 w1 = cmul(Wv, X1[d]);
            float2 Gp = cadd(X0[d], w1);      // v = f
            float2 Gm = csub(X0[d], w1);      // v = f + 512
            const int f = fbase + 64 * (((d & 1) << 2) | (d & 2) | (d >> 2));
            float p1 = Gp.x * Gp.x + Gp.y * Gp.y;
            float p2 = Gm.x * Gm.x + Gm.y * Gm.y;

            float cv1 = f + 0.5f;
            float cv2 = f - 511.5f;
            float d1 = sqrtf(cu * cu + cv1 * cv1);
            float d2 = sqrtf(cu * cu + cv2 * cv2);
            if (d1 < (float)RADIUS) atomicAdd(&mybins[(int)d1], p1);
            if (d2 < (float)RADIUS) atomicAdd(&mybins[(int)d2], p2);
            if (dbl) {
                int v1m = (1024 - f) & 1023;
                int v2m = 512 - f;
                float cv1m = (v1m < 512) ? (v1m + 0.5f) : (v1m - 1023.5f);
                float cv2m = (v2m < 512) ? (v2m + 0.5f) : (v2m - 1023.5f);
                float d1m = sqrtf(cum * cum + cv1m * cv1m);
                float d2m = sqrtf(cum * cum + cv2m * cv2m);
                if (d1m < (float)RADIUS) atomicAdd(&mybins[(int)d1m], p1);
                if (d2m < (float)RADIUS) atomicAdd(&mybins[(int)d2m], p2);
            }
        }
    }
    __syncthreads();
    // fold 4 wave-copies, write per-block partial (every slot, re-poison safe)
    float* dst = partial + ((size_t)g * PBX + blockIdx.x) * RADIUS;
    for (int j = t; j < RADIUS; j += 256) {
        dst[j] = (bins[j] + bins[BSTRIDE + j]) + (bins[2 * BSTRIDE + j] + bins[3 * BSTRIDE + j]);
    }
}

// ---------------------------------------------------------------------------
// Fold partials -> rad
// ---------------------------------------------------------------------------
__global__ __launch_bounds__(256)
void reduce_partials(const float* __restrict__ partial, float* __restrict__ rad) {
    int idx = blockIdx.x * 256 + threadIdx.x;    // 0 .. NIMG*RADIUS-1
    if (idx >= NIMG * RADIUS) return;
    int g = idx >> 9, j = idx & (RADIUS - 1);
    const float* p = partial + (size_t)g * PBX * RADIUS + j;
    float s = 0.0f;
    for (int b = 0; b < PBX; ++b) s += p[(size_t)b * RADIUS];
    rad[idx] = s;
}

// ---------------------------------------------------------------------------
// Final: loss = mean(|rad_out - rad_tgt|) / S^2
// ---------------------------------------------------------------------------
__global__ __launch_bounds__(256)
void final_loss(const float* __restrict__ rad, float* __restrict__ out) {
    __shared__ float red[256];
    const int t = threadIdx.x;
    float acc = 0.0f;
    for (int i = t; i < 16 * RADIUS; i += 256) {
        int bb = i >> 9;
        int rr = i & (RADIUS - 1);
        float o = rad[(size_t)bb * RADIUS + rr];
        float gg = rad[(size_t)(bb + 16) * RADIUS + rr];
        acc += fabsf(o - gg);
    }
    red[t] = acc;
    __syncthreads();
    for (int off = 128; off > 0; off >>= 1) {
        if (t < off) red[t] += red[t + off];
        __syncthreads();
    }
    if (t == 0) {
        out[0] = red[0] / ((float)S * (float)S) / (16.0f * (float)RADIUS);
    }
}

extern "C" void kernel_launch(void* const* d_in, const int* in_sizes, int n_in,
                              void* d_out, int out_size, void* d_ws, size_t ws_size,
                              hipStream_t stream) {
    const float* outp = (const float*)d_in[0];
    const float* tgtp = (const float*)d_in[1];
    float* dout = (float*)d_out;

    char* ws = (char*)d_ws;
    float* rad = (float*)ws;                                       // 64 KB
    const size_t partBytes = (size_t)NIMG * PBX * RADIUS * sizeof(float);  // 8.45 MB
    float* partial = (float*)(ws + 65536);
    float2* WpT = (float2*)(ws + 65536 + partBytes);
    const size_t perImg = (size_t)512 * 1024 * sizeof(float2);     // 4 MB / image
    size_t used = 65536 + partBytes;
    size_t avail = (ws_size > used) ? (ws_size - used) : 0;
    int chunk = (int)(avail / perImg);
    if (chunk > NIMG) chunk = NIMG;
    if (chunk < 1) chunk = 1;

    for (int base = 0; base < NIMG; base += chunk) {
        int c = (NIMG - base < chunk) ? (NIMG - base) : chunk;
        fft_rows<<<dim3(64, c), 512, 0, stream>>>(outp, tgtp, WpT, base);
        fft_cols_bin<<<dim3(PBX, c), 256, 0, stream>>>(WpT, partial, base);
    }

    reduce_partials<<<(NIMG * RADIUS + 255) / 256, 256, 0, stream>>>(partial, rad);
    final_loss<<<1, 256, 0, stream>>>(rad, dout);
}